// Round 12
// baseline (134.633 us; speedup 1.0000x reference)
//
#include <hip/hip_runtime.h>
#include <hip/hip_fp16.h>
#include <stdint.h>

// Local-window (5x5) KDE histogram entropy, 256 bins, bandwidth 0.1.
// sigma'((x-b)/0.1) ~ exp(-10|x-b|): only bins b0=floor(v), b0+1 carry mass.
// Register-resident O(25^2) prefix-merge, telescoping T = sum_b M ln M via
// T += g(P+k)-g(P); H = ln S - T/S.  Numerics identical to R9/R10/R11.
//
// R12 = R11 x3 DIAGNOSTIC. Since R7 the kernel (~33us) is faster than the
// harness's 40us ws-poison fills -> invisible to top-5 rocprof; rounds 8-11
// flew blind and 3 theories died. This round replicates the identical work
// 3x via blockIdx.y (rep 0 -> d_out, reps 1,2 -> disjoint d_ws regions;
// same work every call, graph-safe) so the dispatch lands top-1 and we
// finally read VGPR/spill-traffic/VALUBusy/Occupancy for this structure.
//   role A: T-terms i in [0,18)  (153 pairs);  role B: i in [18,25) (147).

#define W 96
#define H 96
#define TPB 256
#define SPLIT 18

template<int NB, int I0>
__device__ __forceinline__ void role_compute(const float* __restrict__ base,
                                             int xcol, int y,
                                             float& Sout, float& Tout)
{
    int b0a[NB]; uint32_t pk[NB];
    float S = 0.f;
    #pragma unroll
    for (int i = 0; i < NB; ++i) {
        const int dy = i / 5 - 2, dx = i % 5 - 2;
        const int yy = y + dy,    xx = xcol + dx;
        const bool ok = (yy >= 0) & (yy < H) & (xx >= 0) & (xx < W);
        const float v  = base[min(max(yy, 0), H - 1) * W + min(max(xx, 0), W - 1)];
        const int   b0 = (int)v;                    // v in [0,255) -> [0,254]
        const float f  = v - (float)b0;
        const float E  = __expf(-10.f * f);
        const float E2 = __expf(10.f * f - 10.f);
        const float r0 = __builtin_amdgcn_rcpf(1.f + E);
        const float r1 = __builtin_amdgcn_rcpf(1.f + E2);
        const float k0 = ok ? E  * r0 * r0 : 0.f;
        const float k1 = ok ? E2 * r1 * r1 : 0.f;
        const __half2 hk = __floats2half2_rn(k0, k1);
        if (i >= I0) {
            const float2 kc = __half22float2(hk);
            S += kc.x + kc.y;
        }
        b0a[i] = b0;
        pk[i]  = __builtin_bit_cast(uint32_t, hk);
    }

    float T0 = 0.f, T1 = 0.f;
    #pragma unroll
    for (int i = I0; i < NB; ++i) {
        const int b0i = b0a[i];
        uint32_t Ppk = 0u;
        #pragma unroll
        for (int j = 0; j < i; ++j) {
            const int d = b0i - b0a[j];
            int s = 16 * d + 32;
            s = s < 0 ? 0 : (s > 63 ? 63 : s);      // v_med3_i32
            const uint32_t t = (uint32_t)((((uint64_t)pk[j]) << 32) >> s);
            const __half2 sum = __hadd2(__builtin_bit_cast(__half2, Ppk),
                                        __builtin_bit_cast(__half2, t));
            Ppk = __builtin_bit_cast(uint32_t, sum);
        }
        const float2 P  = __half22float2(__builtin_bit_cast(__half2, Ppk));
        const float2 kc = __half22float2(__builtin_bit_cast(__half2, pk[i]));
        const float z0 = P.x + kc.x, z1 = P.y + kc.y;
        const float t4 = z0 * __logf(z0 + 1e-10f) - P.x * __logf(P.x + 1e-10f)
                       + z1 * __logf(z1 + 1e-10f) - P.y * __logf(P.y + 1e-10f);
        if (i & 1) T1 += t4; else T0 += t4;
    }
    Sout = S;
    Tout = T0 + T1;
}

__global__ __launch_bounds__(TPB) void entropy_kde_kernel(
    const float* __restrict__ x, float* __restrict__ out,
    float* __restrict__ ws, int total)
{
    __shared__ float sS[128], sT[128];
    const int tid  = threadIdx.x;
    const int wv   = tid >> 6;          // wave 0..3
    const int g    = wv >> 1;           // pixel group 0/1 (64 px each)
    const int r    = wv & 1;            // role: 0 = A (i<18), 1 = B (i>=18)
    const int l    = tid & 63;
    const int slot = g * 64 + l;
    const int px   = blockIdx.x * 128 + slot;
    const int rep  = blockIdx.y;        // 0,1,2: identical work, 3x for rocprof

    const int xcol = px % W;
    const int y    = (px / W) % H;
    const int img  = px / (W * H);
    const float* __restrict__ base = x + img * (H * W);

    float S, T;
    if (r == 0) role_compute<SPLIT, 0>(base, xcol, y, S, T);
    else        role_compute<25, SPLIT>(base, xcol, y, S, T);

    if (r == 1) { sS[slot] = S; sT[slot] = T; }
    __syncthreads();
    if (r == 0) {
        S += sS[slot];
        T += sT[slot];
        const float Sp = S + 1e-10f;
        float* __restrict__ dst = (rep == 0) ? out : (ws + (rep - 1) * total);
        if (px < total) dst[px] = __logf(Sp) - T / Sp;
    }
}

extern "C" void kernel_launch(void* const* d_in, const int* in_sizes, int n_in,
                              void* d_out, int out_size, void* d_ws, size_t ws_size,
                              hipStream_t stream)
{
    const float* x = (const float*)d_in[0];
    float* out = (float*)d_out;
    float* ws  = (float*)d_ws;                         // >= 2*total*4B, poisoned each call
    const int total  = in_sizes[0];                    // 8*3*96*96 = 221184
    dim3 grid(total / 128, 3, 1);                      // (1728, 3): rep in y
    entropy_kde_kernel<<<grid, TPB, 0, stream>>>(x, out, ws, total);
}

// Round 13
// 77.614 us; speedup vs baseline: 1.7347x; 1.7347x over previous
//
#include <hip/hip_runtime.h>
#include <hip/hip_fp16.h>
#include <stdint.h>

// Local-window (5x5) KDE histogram entropy, 256 bins, bandwidth 0.1.
// sigma'((x-b)/0.1) ~ exp(-10|x-b|): only bins b0=floor(v), b0+1 carry mass
// (truncation err ~2e-3 vs 6.28e-2 threshold; validated R5-R12).
// Register-resident O(25^2) prefix-merge, telescoping T = sum_b M ln M via
// T += g(P+k)-g(P); H = ln S - T/S.
//
// R13: R12's counters showed VALU-issue-bound (VALUBusy 88.5%, no spills,
// occupancy 28%) -> only op-count cuts help. Biggest waste: each input
// pixel's mass (2 exp + 2 rcp + ~20 VALU) was recomputed 43x chip-wide
// (25 overlapping windows x 1.72 role-split redundancy). Two-pass fix:
//   pass 1: per input pixel, compute (pk = fp16(k1|k0), b0) ONCE -> d_ws
//   pass 2: windows LOAD 8B/tap from ws (L2-resident, 1.77MB) and run the
//           unchanged prefix-merge. OOB taps: pk=0 (bit-identical to R11's
//           masking: z==P -> telescoping term cancels exactly).
// Roles unchanged: A = T-terms i in [0,18) (153 pairs), B = [18,25) (147).
// Pair body: t = (u32)(((u64)pj << 32) >> med3(16d+32,0,63)); pk_add_f16.

#define W 96
#define H 96
#define TPB 256
#define SPLIT 18

__global__ __launch_bounds__(TPB) void mass_kernel(
    const float* __restrict__ x, uint2* __restrict__ wm, int total)
{
    const int pid = blockIdx.x * TPB + threadIdx.x;
    if (pid >= total) return;
    const float v  = x[pid];
    const int   b0 = (int)v;                    // v in [0,255) -> [0,254]
    const float f  = v - (float)b0;
    const float E  = __expf(-10.f * f);
    const float E2 = __expf(10.f * f - 10.f);
    const float r0 = __builtin_amdgcn_rcpf(1.f + E);
    const float r1 = __builtin_amdgcn_rcpf(1.f + E2);
    const float k0 = E  * r0 * r0;              // mass at bin b0
    const float k1 = E2 * r1 * r1;              // mass at bin b0+1
    const __half2 hk = __floats2half2_rn(k0, k1);
    wm[pid] = make_uint2(__builtin_bit_cast(uint32_t, hk), (uint32_t)b0);
}

template<int NB, int I0>
__device__ __forceinline__ void role_compute(const uint2* __restrict__ wb,
                                             int xcol, int y,
                                             float& Sout, float& Tout)
{
    int b0a[NB]; uint32_t pk[NB];
    float S = 0.f;
    #pragma unroll
    for (int i = 0; i < NB; ++i) {
        const int dy = i / 5 - 2, dx = i % 5 - 2;
        const int yy = y + dy,    xx = xcol + dx;
        const bool ok = (yy >= 0) & (yy < H) & (xx >= 0) & (xx < W);
        const uint2 m = wb[min(max(yy, 0), H - 1) * W + min(max(xx, 0), W - 1)];
        pk[i]  = ok ? m.x : 0u;                 // zero mass == R11's masking
        b0a[i] = (int)m.y;
        if (i >= I0) {                          // S over my T-range only
            const float2 kc = __half22float2(__builtin_bit_cast(__half2, pk[i]));
            S += kc.x + kc.y;
        }
    }

    float T0 = 0.f, T1 = 0.f;
    #pragma unroll
    for (int i = I0; i < NB; ++i) {
        const int b0i = b0a[i];
        uint32_t Ppk = 0u;
        #pragma unroll
        for (int j = 0; j < i; ++j) {
            const int d = b0i - b0a[j];
            int s = 16 * d + 32;
            s = s < 0 ? 0 : (s > 63 ? 63 : s);  // v_med3_i32
            const uint32_t t = (uint32_t)((((uint64_t)pk[j]) << 32) >> s);
            const __half2 sum = __hadd2(__builtin_bit_cast(__half2, Ppk),
                                        __builtin_bit_cast(__half2, t));
            Ppk = __builtin_bit_cast(uint32_t, sum);
        }
        const float2 P  = __half22float2(__builtin_bit_cast(__half2, Ppk));
        const float2 kc = __half22float2(__builtin_bit_cast(__half2, pk[i]));
        const float z0 = P.x + kc.x, z1 = P.y + kc.y;
        // g(z)=z ln(z+eps); g(0)=0; pk=0 (OOB) -> z==P -> term cancels
        const float t4 = z0 * __logf(z0 + 1e-10f) - P.x * __logf(P.x + 1e-10f)
                       + z1 * __logf(z1 + 1e-10f) - P.y * __logf(P.y + 1e-10f);
        if (i & 1) T1 += t4; else T0 += t4;
    }
    Sout = S;
    Tout = T0 + T1;
}

__global__ __launch_bounds__(TPB) void entropy_kde_kernel(
    const uint2* __restrict__ wm, float* __restrict__ out, int total)
{
    __shared__ float sS[128], sT[128];
    const int tid  = threadIdx.x;
    const int wv   = tid >> 6;          // wave 0..3
    const int g    = wv >> 1;           // pixel group 0/1 (64 px each)
    const int r    = wv & 1;            // role: 0 = A (i<18), 1 = B (i>=18)
    const int l    = tid & 63;
    const int slot = g * 64 + l;
    const int px   = blockIdx.x * 128 + slot;

    const int xcol = px % W;
    const int y    = (px / W) % H;
    const int img  = px / (W * H);
    const uint2* __restrict__ wb = wm + img * (H * W);

    float S, T;
    if (r == 0) role_compute<SPLIT, 0>(wb, xcol, y, S, T);
    else        role_compute<25, SPLIT>(wb, xcol, y, S, T);

    if (r == 1) { sS[slot] = S; sT[slot] = T; }
    __syncthreads();
    if (r == 0) {
        S += sS[slot];
        T += sT[slot];
        const float Sp = S + 1e-10f;
        if (px < total) out[px] = __logf(Sp) - T / Sp;
    }
}

extern "C" void kernel_launch(void* const* d_in, const int* in_sizes, int n_in,
                              void* d_out, int out_size, void* d_ws, size_t ws_size,
                              hipStream_t stream)
{
    const float* x = (const float*)d_in[0];
    float* out = (float*)d_out;
    uint2* wm  = (uint2*)d_ws;                         // 221184*8B = 1.77MB
    const int total = in_sizes[0];                     // 8*3*96*96 = 221184
    mass_kernel<<<(total + TPB - 1) / TPB, TPB, 0, stream>>>(x, wm, total);
    entropy_kde_kernel<<<total / 128, TPB, 0, stream>>>(wm, out, total);
}

// Round 14
// 73.445 us; speedup vs baseline: 1.8331x; 1.0568x over previous
//
#include <hip/hip_runtime.h>
#include <hip/hip_fp16.h>
#include <stdint.h>

// Local-window (5x5) KDE histogram entropy, 256 bins, bandwidth 0.1.
// sigma'((x-b)/0.1) ~ exp(-10|x-b|): only bins b0=floor(v), b0+1 carry mass
// (truncation err ~2e-3 vs 6.28e-2 threshold; validated R5-R13).
// Register-resident O(25^2) prefix-merge, telescoping T2 = sum_b M log2 M via
// T2 += h(P+k)-h(P), h(z)=z log2(z+eps); H = ln2*(log2 S - T2/S).
//
// R14: R12 ground truth = VALU-issue-bound (88.5% busy, no spills). R13's
// mass-dedup moved only 6% -> pair loop + logs dominate. Cuts:
//  (1) pk64[] pre-shifted u64 masses -> 5-op pair body:
//      d=b0i-b0j; s=med3(16d+32,0,63); t=lo32(pk64[j]>>s); Ppk=pk_add(Ppk,t)
//      (d=0 -> pk; 1 -> pk>>16; -1 -> pk<<16; |d|>=2 -> 0, fp16 sign bit=0)
//  (2) halo-padded ws (100x100/img, sentinel pk=0,b0=-32768,k=0): taps are
//      25 unconditional dwordx4 loads at base+imm -> no clamps, no cndmasks
//  (3) log2 domain (bare v_log_f32), single ln2 scale at the end; k0,k1
//      stored f32 in ws (no unpack); role split dropped (VALU-bound => waves
//      don't matter, split overhead does).

#define W   96
#define H   96
#define WP  100          // padded side
#define IMG (W*H)        // 9216
#define IMGP (WP*WP)     // 10000
#define TPB 256

__global__ __launch_bounds__(TPB) void mass_kernel(
    const float* __restrict__ x, uint4* __restrict__ wm, int total2)
{
    const int pid = blockIdx.x * TPB + threadIdx.x;
    if (pid >= total2) return;
    const int x2  = pid % WP;
    const int y2  = (pid / WP) % WP;
    const int img = pid / IMGP;

    uint4 e;
    if (x2 >= 2 && x2 < WP - 2 && y2 >= 2 && y2 < WP - 2) {
        const float v  = x[img * IMG + (y2 - 2) * W + (x2 - 2)];
        const int   b0 = (int)v;                    // v in [0,255) -> [0,254]
        const float f  = v - (float)b0;
        const float E  = __expf(-10.f * f);
        const float E2 = __expf(10.f * f - 10.f);
        const float r0 = __builtin_amdgcn_rcpf(1.f + E);
        const float r1 = __builtin_amdgcn_rcpf(1.f + E2);
        const float k0 = E  * r0 * r0;              // mass at bin b0
        const float k1 = E2 * r1 * r1;              // mass at bin b0+1
        const __half2 hk = __floats2half2_rn(k0, k1);
        const float2  kc = __half22float2(hk);      // fp16-rounded, used in S,T
        e.x = __builtin_bit_cast(uint32_t, hk);
        e.y = (uint32_t)b0;
        e.z = __builtin_bit_cast(uint32_t, kc.x);
        e.w = __builtin_bit_cast(uint32_t, kc.y);
    } else {
        e.x = 0u;                                   // zero mass
        e.y = (uint32_t)(int)(-32768);              // never collides
        e.z = 0u;
        e.w = 0u;
    }
    wm[pid] = e;
}

__global__ __launch_bounds__(TPB) void entropy_kde_kernel(
    const uint4* __restrict__ wm, float* __restrict__ out)
{
    const int px   = blockIdx.x * TPB + threadIdx.x;  // grid exact: 864*256
    const int xcol = px % W;
    const int y    = (px / W) % H;
    const int img  = px / IMG;
    // padded base: tap(dy,dx) = base + (dy+2)*WP + (dx+2), offsets 0..404
    const uint4* __restrict__ wb = wm + img * IMGP + y * WP + xcol;

    uint64_t pk64[25];
    int      b0a [25];
    float S0 = 0.f, S1 = 0.f;
    float T0 = 0.f, T1 = 0.f, T2a = 0.f, T3 = 0.f;

    #pragma unroll
    for (int i = 0; i < 25; ++i) {
        const int dy = i / 5, dx = i % 5;            // 0..4 (already +2 shifted)
        const uint4 m = wb[dy * WP + dx];            // base + imm offset
        const int   b0i = (int)m.y;
        const float k0  = __builtin_bit_cast(float, m.z);
        const float k1  = __builtin_bit_cast(float, m.w);
        if (i & 1) S1 += k0 + k1; else S0 += k0 + k1;

        uint32_t Ppk = 0u;
        #pragma unroll
        for (int j = 0; j < i; ++j) {
            const int d = b0i - b0a[j];
            int s = (d << 4) + 32;
            s = s < 0 ? 0 : (s > 63 ? 63 : s);       // v_med3_i32
            const uint32_t t = (uint32_t)(pk64[j] >> s);
            const __half2 sum = __hadd2(__builtin_bit_cast(__half2, Ppk),
                                        __builtin_bit_cast(__half2, t));
            Ppk = __builtin_bit_cast(uint32_t, sum);
        }
        const float2 P  = __half22float2(__builtin_bit_cast(__half2, Ppk));
        const float z0 = P.x + k0, z1 = P.y + k1;
        // h(z) = z*log2(z+eps); h(0)=0; k=0 (sentinel) -> z==P -> cancels
        const float t4 = z0  * __log2f(z0  + 1e-10f) - P.x * __log2f(P.x + 1e-10f)
                       + z1  * __log2f(z1  + 1e-10f) - P.y * __log2f(P.y + 1e-10f);
        if      ((i & 3) == 0) T0  += t4;
        else if ((i & 3) == 1) T1  += t4;
        else if ((i & 3) == 2) T2a += t4;
        else                   T3  += t4;

        b0a[i]  = b0i;
        pk64[i] = ((uint64_t)m.x) << 32;
    }

    const float S  = (S0 + S1) + 1e-10f;
    const float T  = (T0 + T1) + (T2a + T3);
    // H = ln S - (sum m ln m)/S = ln2 * (log2 S - T/S)
    out[px] = 0.69314718056f * (__log2f(S) - T / S);
}

extern "C" void kernel_launch(void* const* d_in, const int* in_sizes, int n_in,
                              void* d_out, int out_size, void* d_ws, size_t ws_size,
                              hipStream_t stream)
{
    const float* x = (const float*)d_in[0];
    float* out = (float*)d_out;
    uint4* wm  = (uint4*)d_ws;                       // 24*10000*16B = 3.84 MB
    const int total  = in_sizes[0];                  // 8*3*96*96 = 221184
    const int total2 = (total / IMG) * IMGP;         // 240000 padded entries
    mass_kernel<<<(total2 + TPB - 1) / TPB, TPB, 0, stream>>>(x, wm, total2);
    entropy_kde_kernel<<<total / TPB, TPB, 0, stream>>>(wm, out);
}

// Round 15
// 70.238 us; speedup vs baseline: 1.9168x; 1.0457x over previous
//
#include <hip/hip_runtime.h>
#include <hip/hip_fp16.h>
#include <stdint.h>

// Local-window (5x5) KDE histogram entropy, 256 bins, bandwidth 0.1.
// sigma'((x-b)/0.1) ~ exp(-10|x-b|): only bins b0=floor(v), b0+1 carry mass
// (truncation err ~2e-3 vs 6.28e-2 threshold; validated R5-R14).
// Register-resident O(25^2) prefix-merge, telescoping T2 = sum_b M log2 M;
// H = ln2*(log2 S - T2/S).
//
// R15: R12-calibrated model says per-wave VALU is ~2.5-3x the hand count;
// prime suspect is __log2f -> __ocml_log2_f32 denormal-fixup wrapper (~6
// extra VALU x 100 logs/px = the largest single bucket; our +1e-10 eps makes
// the fixup dead weight). Cuts:
//  (1) bare v_log_f32 (builtin if present, else asm + s_nop 1 for the
//      gfx9 trans-use hazard, since inline-asm contents are opaque to the
//      backend's hazard recognizer)
//  (2) 4-op pair body: pass1 stores b0<<4; s = med3(A_i - b0sh_j, 0, 63),
//      A_i = b0sh_i + 32; t = lo32(pk64_j >> s); Ppk = pk_add_f16(Ppk, t)
//      d=0->pk; 1->pk>>16; -1->pk<<16; clamp ends give 0 (lo dword 0 /
//      bit63 = fp16 sign = 0). Sentinel b0sh = 1<<20 forces clamp ends.
//  (3) epilogue log bare too.

#define W   96
#define H   96
#define WP  100          // padded side
#define IMG (W*H)        // 9216
#define IMGP (WP*WP)     // 10000
#define TPB 256

#if __has_builtin(__builtin_amdgcn_logf)
__device__ __forceinline__ float rawlog2(float v) {
    return __builtin_amdgcn_logf(v);
}
#else
__device__ __forceinline__ float rawlog2(float v) {
    float r;
    asm("v_log_f32 %0, %1\n\ts_nop 1" : "=v"(r) : "v"(v));
    return r;
}
#endif

__global__ __launch_bounds__(TPB) void mass_kernel(
    const float* __restrict__ x, uint4* __restrict__ wm, int total2)
{
    const int pid = blockIdx.x * TPB + threadIdx.x;
    if (pid >= total2) return;
    const int x2  = pid % WP;
    const int y2  = (pid / WP) % WP;
    const int img = pid / IMGP;

    uint4 e;
    if (x2 >= 2 && x2 < WP - 2 && y2 >= 2 && y2 < WP - 2) {
        const float v  = x[img * IMG + (y2 - 2) * W + (x2 - 2)];
        const int   b0 = (int)v;                    // v in [0,255) -> [0,254]
        const float f  = v - (float)b0;
        const float E  = __expf(-10.f * f);
        const float E2 = __expf(10.f * f - 10.f);
        const float r0 = __builtin_amdgcn_rcpf(1.f + E);
        const float r1 = __builtin_amdgcn_rcpf(1.f + E2);
        const float k0 = E  * r0 * r0;              // mass at bin b0
        const float k1 = E2 * r1 * r1;              // mass at bin b0+1
        const __half2 hk = __floats2half2_rn(k0, k1);
        const float2  kc = __half22float2(hk);      // fp16-rounded, used in S,T
        e.x = __builtin_bit_cast(uint32_t, hk);
        e.y = (uint32_t)(b0 << 4);                  // pre-shifted for pair body
        e.z = __builtin_bit_cast(uint32_t, kc.x);
        e.w = __builtin_bit_cast(uint32_t, kc.y);
    } else {
        e.x = 0u;                                   // zero mass
        e.y = (uint32_t)(1 << 20);                  // clamps s to an end -> t=0
        e.z = 0u;
        e.w = 0u;
    }
    wm[pid] = e;
}

__global__ __launch_bounds__(TPB) void entropy_kde_kernel(
    const uint4* __restrict__ wm, float* __restrict__ out)
{
    const int px   = blockIdx.x * TPB + threadIdx.x;  // grid exact: 864*256
    const int xcol = px % W;
    const int y    = (px / W) % H;
    const int img  = px / IMG;
    // padded base: tap(dy,dx) = base + dy*WP + dx, dy,dx in 0..4
    const uint4* __restrict__ wb = wm + img * IMGP + y * WP + xcol;

    uint64_t pk64[25];
    int      bsh [25];
    float S0 = 0.f, S1 = 0.f;
    float T0 = 0.f, T1 = 0.f, T2a = 0.f, T3 = 0.f;

    #pragma unroll
    for (int i = 0; i < 25; ++i) {
        const int dy = i / 5, dx = i % 5;
        const uint4 m = wb[dy * WP + dx];            // base + imm offset
        const int   A  = (int)m.y + 32;              // b0i<<4 + 32
        const float k0 = __builtin_bit_cast(float, m.z);
        const float k1 = __builtin_bit_cast(float, m.w);
        if (i & 1) S1 += k0 + k1; else S0 += k0 + k1;

        uint32_t Ppk = 0u;
        #pragma unroll
        for (int j = 0; j < i; ++j) {
            int s = A - bsh[j];                      // 16d + 32
            s = s < 0 ? 0 : (s > 63 ? 63 : s);       // v_med3_i32
            const uint32_t t = (uint32_t)(pk64[j] >> s);
            const __half2 sum = __hadd2(__builtin_bit_cast(__half2, Ppk),
                                        __builtin_bit_cast(__half2, t));
            Ppk = __builtin_bit_cast(uint32_t, sum);
        }
        const float2 P  = __half22float2(__builtin_bit_cast(__half2, Ppk));
        const float z0 = P.x + k0, z1 = P.y + k1;
        // h(z) = z*log2(z+eps); h(0)=0; k=0 (sentinel) -> z==P -> cancels
        const float t4 = z0  * rawlog2(z0  + 1e-10f) - P.x * rawlog2(P.x + 1e-10f)
                       + z1  * rawlog2(z1  + 1e-10f) - P.y * rawlog2(P.y + 1e-10f);
        if      ((i & 3) == 0) T0  += t4;
        else if ((i & 3) == 1) T1  += t4;
        else if ((i & 3) == 2) T2a += t4;
        else                   T3  += t4;

        bsh[i]  = (int)m.y;
        pk64[i] = ((uint64_t)m.x) << 32;
    }

    const float S  = (S0 + S1) + 1e-10f;
    const float T  = (T0 + T1) + (T2a + T3);
    // H = ln S - (sum m ln m)/S = ln2 * (log2 S - T/S)
    out[px] = 0.69314718056f * (rawlog2(S) - T / S);
}

extern "C" void kernel_launch(void* const* d_in, const int* in_sizes, int n_in,
                              void* d_out, int out_size, void* d_ws, size_t ws_size,
                              hipStream_t stream)
{
    const float* x = (const float*)d_in[0];
    float* out = (float*)d_out;
    uint4* wm  = (uint4*)d_ws;                       // 24*10000*16B = 3.84 MB
    const int total  = in_sizes[0];                  // 8*3*96*96 = 221184
    const int total2 = (total / IMG) * IMGP;         // 240000 padded entries
    mass_kernel<<<(total2 + TPB - 1) / TPB, TPB, 0, stream>>>(x, wm, total2);
    entropy_kde_kernel<<<total / TPB, TPB, 0, stream>>>(wm, out);
}